// Round 3
// baseline (472.004 us; speedup 1.0000x reference)
//
#include <hip/hip_runtime.h>

#define Mc 512
#define Nc 1024
#define WRc 16
#define Bc 4096

// c2v state indexed by step-slot s = t mod 512 (cn_order is a per-sweep
// permutation reused identically every sweep). Layout [s][b][j]; slot offset
// uniform (s<<16 elements), lane part (b*16+j) loop-invariant. Sweep 0 never
// reads it -> no init needed (idempotent across launches).
__device__ float g_c2v[(size_t)Mc * Bc * WRc];

// Permuted H rows with static hazard flags, produced by flags_kernel:
//   bits 0-9 : column index
//   bit 15   : overlap(row s, row s-1)  (intra-pair hazard)
//   bit 14   : overlap(row s, row s-2)
//   bit 13   : overlap(row s, row s-3)
__device__ __align__(16) unsigned short g_hp[Mc * WRc];

#define DPPI(old, src, ctrl) \
  __builtin_amdgcn_update_dpp((old), (src), (ctrl), 0xF, 0xF, false)

static __device__ __forceinline__ int imin(int a, int b) { return a < b ? a : b; }

// Min-sum check-node message: exclusive leave-one-out |min| via prefix/suffix
// DPP int-min scans + sign parity via 4 row_ror XORs (no ballot: keeps the
// whole computation on VALU, no SGPR round-trip, and two concurrent calls
// share no vcc -> fully independent chains).
static __device__ __forceinline__ float check_msg(float v2c) {
  const int INFB = 0x7FFFFFFF;
  const int vb = __float_as_int(v2c);
  const int ab = vb & 0x7FFFFFFF;
  int p = ab;
  p = imin(p, DPPI(INFB, p, 0x111));  // row_shr:1
  p = imin(p, DPPI(INFB, p, 0x112));
  p = imin(p, DPPI(INFB, p, 0x114));
  p = imin(p, DPPI(INFB, p, 0x118));
  int s2 = ab;
  s2 = imin(s2, DPPI(INFB, s2, 0x101));  // row_shl:1
  s2 = imin(s2, DPPI(INFB, s2, 0x102));
  s2 = imin(s2, DPPI(INFB, s2, 0x104));
  s2 = imin(s2, DPPI(INFB, s2, 0x108));
  const int loo = imin(DPPI(INFB, p, 0x111), DPPI(INFB, s2, 0x101));
  // parity of sign bits across the 16-lane row via ror-xor butterfly
  int x = vb;
  x ^= DPPI(0, x, 0x121);  // row_ror:1
  x ^= DPPI(0, x, 0x122);  // row_ror:2
  x ^= DPPI(0, x, 0x124);  // row_ror:4
  x ^= DPPI(0, x, 0x128);  // row_ror:8
  const int negb = (x ^ vb) & 0x80000000;  // parity of the OTHER 15 lanes
  return __int_as_float(imin(0x41A00000 /*20.0f*/, loo) | negb);
}

// One PAIR of consecutive rows (tA = tb+2k, tB = tA+1).
// Top of body: issue speculative gathers for pair P+1 (they miss ONLY this
// pair's scatters) and the hp reads for pair P+2 (one pair of slack).
// End of body: re-gather any flagged row (post-scatter, exposed latency only
// when static flags say the speculation was unsafe).
#define PAIR(k, ZEROC, LOADC, STOREC)                                       \
  {                                                                         \
    const int tA = tb + 2 * (k);                                            \
    const int iA1m = iA1 & 1023, iB1m = iB1 & 1023;                         \
    float vA1 = vng[iA1m]; /* early gather, pair P+1 row A */               \
    float vB1 = vng[iB1m]; /* early gather, pair P+1 row B */               \
    const int iA2 = hp[((tA + 4) & 511) * WRc + j];                         \
    const int iB2 = hp[((tA + 5) & 511) * WRc + j];                         \
    const int iAm = iA & 1023, iBm = iB & 1023;                             \
    float ncA, ncB;                                                         \
    const float v2cA = (ZEROC) ? vA : (vA - c2vf[2 * (k)]);                 \
    if (__builtin_amdgcn_readfirstlane(iB) & 0x8000) {                      \
      /* intra-pair overlap: strict sequential order */                     \
      ncA = check_msg(v2cA);                                                \
      vng[iAm] = v2cA + ncA;                                                \
      const float vBr = vng[iBm]; /* re-gather after scatter A */           \
      const float v2cB = (ZEROC) ? vBr : (vBr - c2vf[2 * (k) + 1]);         \
      ncB = check_msg(v2cB);                                                \
      vng[iBm] = v2cB + ncB;                                                \
    } else {                                                                \
      const float v2cB = (ZEROC) ? vB : (vB - c2vf[2 * (k) + 1]);           \
      ncA = check_msg(v2cA);                                                \
      ncB = check_msg(v2cB);                                                \
      vng[iAm] = v2cA + ncA;                                                \
      vng[iBm] = v2cB + ncB;                                                \
    }                                                                       \
    if (STOREC) {                                                           \
      g_c2v[((unsigned)tA << 16) + lane] = ncA;                             \
      g_c2v[(((unsigned)tA + 1u) << 16) + lane] = ncB;                      \
    }                                                                       \
    if (LOADC) {                                                            \
      c2vf[2 * (k)] = g_c2v[((unsigned)((tA + 8) & 511) << 16) + lane];     \
      c2vf[2 * (k) + 1] = g_c2v[((unsigned)((tA + 9) & 511) << 16) + lane]; \
    }                                                                       \
    /* resolve speculation for pair P+1 (post-scatter) */                   \
    const unsigned fa = __builtin_amdgcn_readfirstlane(iA1);                \
    const unsigned fb = __builtin_amdgcn_readfirstlane(iB1);                \
    if (fa & 0xC000u) vA1 = vng[iA1m]; /* dist 1|2 hazard */                \
    if ((fb & 0x6000u) && !(fb & 0x8000u))                                  \
      vB1 = vng[iB1m]; /* dist 2|3 hazard; bit15 -> intra path re-reads */  \
    vA = vA1;                                                               \
    vB = vB1;                                                               \
    iA = iA1;                                                               \
    iB = iB1;                                                               \
    iA1 = iA2;                                                              \
    iB1 = iB2;                                                              \
  }

#define PAIR4(Z, L, S) \
  PAIR(0, Z, L, S) PAIR(1, Z, L, S) PAIR(2, Z, L, S) PAIR(3, Z, L, S)

// Tiny pre-kernel: computes permuted H + static hazard flags ONCE (all 1024
// decoder blocks share identical H/cn_order; recomputing per-block is waste).
__global__ __launch_bounds__(64) void flags_kernel(
    const int* __restrict__ H, const int* __restrict__ cn_order) {
  const int s = blockIdx.x * 64 + threadIdx.x;
  if (s >= Mc) return;
  unsigned short cur[WRc], p1[WRc], p2[WRc], p3[WRc];
  const int r0 = cn_order[s];
  const int r1 = cn_order[(s + Mc - 1) & (Mc - 1)];
  const int r2 = cn_order[(s + Mc - 2) & (Mc - 1)];
  const int r3 = cn_order[(s + Mc - 3) & (Mc - 1)];
  for (int a = 0; a < WRc; ++a) {
    cur[a] = (unsigned short)H[r0 * WRc + a];
    p1[a] = (unsigned short)H[r1 * WRc + a];
    p2[a] = (unsigned short)H[r2 * WRc + a];
    p3[a] = (unsigned short)H[r3 * WRc + a];
  }
  bool o1 = false, o2 = false, o3 = false;
  for (int a = 0; a < WRc; ++a)
    for (int c = 0; c < WRc; ++c) {
      o1 |= (cur[a] == p1[c]);
      o2 |= (cur[a] == p2[c]);
      o3 |= (cur[a] == p3[c]);
    }
  const unsigned f =
      (o1 ? 0x8000u : 0u) | (o2 ? 0x4000u : 0u) | (o3 ? 0x2000u : 0u);
  for (int a = 0; a < WRc; ++a)
    g_hp[s * WRc + a] = (unsigned short)(cur[a] | f);
}

__global__ __launch_bounds__(64) void ldpc_kernel(
    const float* __restrict__ llr, const int* __restrict__ iters_p,
    float* __restrict__ out) {
  const int tid = threadIdx.x;
  const int g = tid >> 4;  // batch sub-slot within wave (0..3)
  const int j = tid & 15;  // edge position within check node
  const int b0 = blockIdx.x * 4;
  const unsigned lane = (unsigned)(b0 * 16 + tid);  // (b*WR + j)

  // Row stride 1032 dwords == 8 (mod 32): bank(g,idx) = (8g + idx) % 32.
  // Intra-group conflicts now collide on idx mod 32 (was mod 8) -> ~2x fewer.
  __shared__ __align__(16) float vn2[4][1032];            // 16.5 KB
  __shared__ __align__(16) unsigned short hp[Mc * WRc];   // 16 KB

  // Vectorized staging (uint4): LLRs for 4 batches + precomputed hp.
  {
    const uint4* src = (const uint4*)(llr + (size_t)b0 * Nc);
    for (int i = tid; i < 1024; i += 64) {
      const uint4 w = src[i];
      *(uint4*)&vn2[i >> 8][(i & 255) * 4] = w;
    }
    const uint4* hsrc = (const uint4*)g_hp;
    for (int i = tid; i < 1024; i += 64) ((uint4*)hp)[i] = hsrc[i];
  }
  __syncthreads();

  const int sweeps = iters_p[0];
  float* const vng = vn2[g];

  // ---- pipeline prime: pair 0 = rows 0,1; pair 1 idx = rows 2,3 ----
  int iA = hp[0 * WRc + j];
  int iB = hp[1 * WRc + j];
  int iA1 = hp[2 * WRc + j];
  int iB1 = hp[3 * WRc + j];
  float vA = vng[iA & 1023];
  float vB = vng[iB & 1023];
  float c2vf[8] = {0, 0, 0, 0, 0, 0, 0, 0};

  int tb;
  if (sweeps >= 2) {
    // Sweep 0 (c2v==0); bridge starts prefetching slots 0..7 for sweep 1.
    for (tb = 0; tb < Mc - 8; tb += 8) { PAIR4(1, 0, 1) }
    { PAIR4(1, 1, 1) }  // tb == 504
    // Middle sweeps: prefetch depth 8 (one unrolled iter -> static c2vf).
    for (int sw = 1; sw < sweeps - 1; ++sw) {
      for (tb = 0; tb < Mc; tb += 8) { PAIR4(0, 1, 1) }
    }
    // Final sweep: c2v stores are never read again -> skip (saves 134 MB);
    // tail also skips the now-useless prefetch loads.
    for (tb = 0; tb < Mc - 8; tb += 8) { PAIR4(0, 1, 0) }
    { PAIR4(0, 0, 0) }  // tb == 504
  } else if (sweeps == 1) {
    for (tb = 0; tb < Mc; tb += 8) { PAIR4(1, 0, 0) }
  }

  // Hard decision (single wave: no barrier needed), vectorized.
  {
    float4* dst = (float4*)(out + (size_t)b0 * Nc);
    for (int i = tid; i < 1024; i += 64) {
      const float4 vv = *(const float4*)&vn2[i >> 8][(i & 255) * 4];
      float4 o;
      o.x = (vv.x < 0.0f) ? 1.0f : 0.0f;
      o.y = (vv.y < 0.0f) ? 1.0f : 0.0f;
      o.z = (vv.z < 0.0f) ? 1.0f : 0.0f;
      o.w = (vv.w < 0.0f) ? 1.0f : 0.0f;
      dst[i] = o;
    }
  }
}

extern "C" void kernel_launch(void* const* d_in, const int* in_sizes, int n_in,
                              void* d_out, int out_size, void* d_ws, size_t ws_size,
                              hipStream_t stream) {
  const float* llr = (const float*)d_in[0];
  const int* H = (const int*)d_in[1];
  const int* iters_p = (const int*)d_in[2];
  const int* cn_order = (const int*)d_in[3];
  float* out = (float*)d_out;
  flags_kernel<<<dim3(8), dim3(64), 0, stream>>>(H, cn_order);
  ldpc_kernel<<<dim3(Bc / 4), dim3(64), 0, stream>>>(llr, iters_p, out);
}

// Round 4
// 456.048 us; speedup vs baseline: 1.0350x; 1.0350x over previous
//
#include <hip/hip_runtime.h>

#define Mc 512
#define Nc 1024
#define WRc 16
#define Bc 4096

// c2v state indexed by step-slot s = t mod 512 (cn_order is a per-sweep
// permutation reused identically every sweep). Layout [s][b][j]; slot offset
// uniform (s<<16 elements), lane part (b*16+j) loop-invariant. Sweep 0 never
// reads it -> no init needed (idempotent across launches).
__device__ float g_c2v[(size_t)Mc * Bc * WRc];

// Permuted H rows with static hazard flags, produced by flags_kernel:
//   bits 0-9 : column index
//   bit 15   : overlap(row s, row s-1)  (intra-pair hazard / spec dist-1)
//   bit 14   : overlap(row s, row s-2)  (spec dist-2)
//   bit 13   : overlap(row s, row s-3)  (unused in this version)
__device__ __align__(16) unsigned short g_hp[Mc * WRc];

#define DPPI(old, src, ctrl) \
  __builtin_amdgcn_update_dpp((old), (src), (ctrl), 0xF, 0xF, false)

static __device__ __forceinline__ int imin(int a, int b) { return a < b ? a : b; }

// Min-sum check-node message: exclusive leave-one-out |min| via prefix/suffix
// DPP int-min scans + sign parity via ror-xor butterfly (all VALU, no vcc ->
// two concurrent calls are fully independent chains the scheduler interleaves).
static __device__ __forceinline__ float check_msg(float v2c) {
  const int INFB = 0x7FFFFFFF;
  const int vb = __float_as_int(v2c);
  const int ab = vb & 0x7FFFFFFF;
  int p = ab;
  p = imin(p, DPPI(INFB, p, 0x111));  // row_shr:1
  p = imin(p, DPPI(INFB, p, 0x112));
  p = imin(p, DPPI(INFB, p, 0x114));
  p = imin(p, DPPI(INFB, p, 0x118));
  int s2 = ab;
  s2 = imin(s2, DPPI(INFB, s2, 0x101));  // row_shl:1
  s2 = imin(s2, DPPI(INFB, s2, 0x102));
  s2 = imin(s2, DPPI(INFB, s2, 0x104));
  s2 = imin(s2, DPPI(INFB, s2, 0x108));
  const int loo = imin(DPPI(INFB, p, 0x111), DPPI(INFB, s2, 0x101));
  int x = vb;
  x ^= DPPI(0, x, 0x121);  // row_ror:1
  x ^= DPPI(0, x, 0x122);  // row_ror:2
  x ^= DPPI(0, x, 0x124);  // row_ror:4
  x ^= DPPI(0, x, 0x128);  // row_ror:8
  const int negb = (x ^ vb) & 0x80000000;  // parity of the OTHER 15 lanes
  return __int_as_float(imin(0x41A00000 /*20.0f*/, loo) | negb);
}

// One PAIR of consecutive rows (tA = tb+2k, tB = tA+1), R2 structure plus
// SPEC-A ONLY: row A of pair P+1 is gathered at the TOP of pair P (misses this
// pair's scatters; re-read post-scatter iff static dist-1|2 flags say hazard,
// ~39%). Row B of pair P+1 is gathered at the END of the pair, after both
// scatters -> always safe, no flags, no conditional def. Once A is ready at
// pair-top, B's gather latency hides under A's scan chain.
// The taken hazard branch drains lgkmcnt to 0 so the waitcnt state at the
// join is exact: the clean path's later use of vA1 needs no new wait.
#define PAIR(k, ZEROC, LOADC, STOREC)                                        \
  {                                                                          \
    const int tA = tb + 2 * (k);                                             \
    const int iA1m = iA1 & 1023;                                             \
    float vA1 = vng[iA1m]; /* speculative gather, pair P+1 row A */          \
    const int iA2 = hp[((tA + 4) & 511) * WRc + j];                          \
    const int iB2 = hp[((tA + 5) & 511) * WRc + j];                          \
    const int iAm = iA & 1023, iBm = iB & 1023;                              \
    float ncA, ncB;                                                          \
    const float v2cA = (ZEROC) ? vA : (vA - c2vf[2 * (k)]);                  \
    if (__builtin_amdgcn_readfirstlane(iB) & 0x8000) {                       \
      /* intra-pair overlap (~22%): strict sequential order */               \
      ncA = check_msg(v2cA);                                                 \
      vng[iAm] = v2cA + ncA;                                                 \
      const float vBr = vng[iBm]; /* re-gather after scatter A */            \
      const float v2cB = (ZEROC) ? vBr : (vBr - c2vf[2 * (k) + 1]);          \
      ncB = check_msg(v2cB);                                                 \
      vng[iBm] = v2cB + ncB;                                                 \
    } else {                                                                 \
      const float v2cB = (ZEROC) ? vB : (vB - c2vf[2 * (k) + 1]);            \
      ncA = check_msg(v2cA);                                                 \
      ncB = check_msg(v2cB);                                                 \
      vng[iAm] = v2cA + ncA;                                                 \
      vng[iBm] = v2cB + ncB;                                                 \
    }                                                                        \
    if (__builtin_amdgcn_readfirstlane(iA1) & 0xC000u) {                     \
      vA1 = vng[iA1m]; /* hazard: re-read post-scatter (~39%) */             \
      asm volatile("s_waitcnt lgkmcnt(0)" ::: "memory");                     \
      __builtin_amdgcn_sched_barrier(0);                                     \
    }                                                                        \
    const float vB1 = vng[iB1 & 1023]; /* safe: after both scatters */       \
    if (STOREC) {                                                            \
      g_c2v[((unsigned)tA << 16) + lane] = ncA;                              \
      g_c2v[(((unsigned)tA + 1u) << 16) + lane] = ncB;                       \
    }                                                                        \
    if (LOADC) {                                                             \
      c2vf[2 * (k)] = g_c2v[((unsigned)((tA + 8) & 511) << 16) + lane];      \
      c2vf[2 * (k) + 1] = g_c2v[((unsigned)((tA + 9) & 511) << 16) + lane];  \
    }                                                                        \
    vA = vA1;                                                                \
    vB = vB1;                                                                \
    iA = iA1;                                                                \
    iB = iB1;                                                                \
    iA1 = iA2;                                                               \
    iB1 = iB2;                                                               \
  }

#define PAIR4(Z, L, S) \
  PAIR(0, Z, L, S) PAIR(1, Z, L, S) PAIR(2, Z, L, S) PAIR(3, Z, L, S)

// Tiny pre-kernel: permuted H + static hazard flags computed ONCE (all 1024
// decoder blocks share identical H/cn_order).
__global__ __launch_bounds__(64) void flags_kernel(
    const int* __restrict__ H, const int* __restrict__ cn_order) {
  const int s = blockIdx.x * 64 + threadIdx.x;
  if (s >= Mc) return;
  unsigned short cur[WRc], p1[WRc], p2[WRc], p3[WRc];
  const int r0 = cn_order[s];
  const int r1 = cn_order[(s + Mc - 1) & (Mc - 1)];
  const int r2 = cn_order[(s + Mc - 2) & (Mc - 1)];
  const int r3 = cn_order[(s + Mc - 3) & (Mc - 1)];
  for (int a = 0; a < WRc; ++a) {
    cur[a] = (unsigned short)H[r0 * WRc + a];
    p1[a] = (unsigned short)H[r1 * WRc + a];
    p2[a] = (unsigned short)H[r2 * WRc + a];
    p3[a] = (unsigned short)H[r3 * WRc + a];
  }
  bool o1 = false, o2 = false, o3 = false;
  for (int a = 0; a < WRc; ++a)
    for (int c = 0; c < WRc; ++c) {
      o1 |= (cur[a] == p1[c]);
      o2 |= (cur[a] == p2[c]);
      o3 |= (cur[a] == p3[c]);
    }
  const unsigned f =
      (o1 ? 0x8000u : 0u) | (o2 ? 0x4000u : 0u) | (o3 ? 0x2000u : 0u);
  for (int a = 0; a < WRc; ++a)
    g_hp[s * WRc + a] = (unsigned short)(cur[a] | f);
}

__global__ __launch_bounds__(64) void ldpc_kernel(
    const float* __restrict__ llr, const int* __restrict__ iters_p,
    float* __restrict__ out) {
  const int tid = threadIdx.x;
  const int g = tid >> 4;  // batch sub-slot within wave (0..3)
  const int j = tid & 15;  // edge position within check node
  const int b0 = blockIdx.x * 4;
  const unsigned lane = (unsigned)(b0 * 16 + tid);  // (b*WR + j)

  // Row stride 1032 dwords == 8 (mod 32): bank(g,idx) = (8g + idx) % 32 ->
  // intra-group conflicts collide on idx mod 32 (was mod 8 with [n][4]).
  __shared__ __align__(16) float vn2[4][1032];           // 16.5 KB
  __shared__ __align__(16) unsigned short hp[Mc * WRc];  // 16 KB

  // Vectorized staging (uint4): LLRs for 4 batches + precomputed hp+flags.
  {
    const uint4* src = (const uint4*)(llr + (size_t)b0 * Nc);
    for (int i = tid; i < 1024; i += 64) {
      const uint4 w = src[i];
      *(uint4*)&vn2[i >> 8][(i & 255) * 4] = w;
    }
    const uint4* hsrc = (const uint4*)g_hp;
    for (int i = tid; i < 1024; i += 64) ((uint4*)hp)[i] = hsrc[i];
  }
  __syncthreads();

  const int sweeps = iters_p[0];
  float* const vng = vn2[g];

  // ---- pipeline prime: pair 0 = rows 0,1; pair 1 idx = rows 2,3 ----
  int iA = hp[0 * WRc + j];
  int iB = hp[1 * WRc + j];
  int iA1 = hp[2 * WRc + j];
  int iB1 = hp[3 * WRc + j];
  float vA = vng[iA & 1023];
  float vB = vng[iB & 1023];
  float c2vf[8] = {0, 0, 0, 0, 0, 0, 0, 0};

  int tb;
  if (sweeps >= 2) {
    // Sweep 0 (c2v==0); bridge starts prefetching slots 0..7 for sweep 1.
    for (tb = 0; tb < Mc - 8; tb += 8) { PAIR4(1, 0, 1) }
    { PAIR4(1, 1, 1) }  // tb == 504
    // Middle sweeps: prefetch depth 8 rows (one unrolled iter -> static
    // c2vf indices -> registers).
    for (int sw = 1; sw < sweeps - 1; ++sw) {
      for (tb = 0; tb < Mc; tb += 8) { PAIR4(0, 1, 1) }
    }
    // Final sweep: c2v stores never read again -> skip (saves 134 MB);
    // tail also skips the now-useless prefetch loads.
    for (tb = 0; tb < Mc - 8; tb += 8) { PAIR4(0, 1, 0) }
    { PAIR4(0, 0, 0) }  // tb == 504
  } else if (sweeps == 1) {
    for (tb = 0; tb < Mc; tb += 8) { PAIR4(1, 0, 0) }
  }

  // Hard decision (single wave: no barrier needed), vectorized.
  {
    float4* dst = (float4*)(out + (size_t)b0 * Nc);
    for (int i = tid; i < 1024; i += 64) {
      const float4 vv = *(const float4*)&vn2[i >> 8][(i & 255) * 4];
      float4 o;
      o.x = (vv.x < 0.0f) ? 1.0f : 0.0f;
      o.y = (vv.y < 0.0f) ? 1.0f : 0.0f;
      o.z = (vv.z < 0.0f) ? 1.0f : 0.0f;
      o.w = (vv.w < 0.0f) ? 1.0f : 0.0f;
      dst[i] = o;
    }
  }
}

extern "C" void kernel_launch(void* const* d_in, const int* in_sizes, int n_in,
                              void* d_out, int out_size, void* d_ws, size_t ws_size,
                              hipStream_t stream) {
  const float* llr = (const float*)d_in[0];
  const int* H = (const int*)d_in[1];
  const int* iters_p = (const int*)d_in[2];
  const int* cn_order = (const int*)d_in[3];
  float* out = (float*)d_out;
  flags_kernel<<<dim3(8), dim3(64), 0, stream>>>(H, cn_order);
  ldpc_kernel<<<dim3(Bc / 4), dim3(64), 0, stream>>>(llr, iters_p, out);
}